// Round 12
// baseline (72.007 us; speedup 1.0000x reference)
//
#include <hip/hip_runtime.h>
#include <cstdint>

static constexpr int B    = 16;
static constexpr int P    = 22536;
static constexpr int NOBJ = 32;
static constexpr int NCLS = 80;
static constexpr int CHUNKS = (P + 255) / 256;   // 89
static constexpr int NBLK   = CHUNKS * B;        // 1424 bulk-role blocks
static constexpr int OBJB   = B * NOBJ;          // 512 objbest-role blocks
static constexpr int RPAD   = 21;                // LDS row pad (coprime 32)

// neg-path focal term (before 0.75 weight): p^2*(x+log u), u=1+e^-x, p=1/u
__device__ __forceinline__ float negterm(float x) {
  float e  = __expf(-x);
  float u  = 1.f + e;
  float r  = __builtin_amdgcn_rcpf(u);
  float lu = __logf(u);
  return (x + lu) * (r * r);
}

// net correction when class x is the positive class (pos term minus its neg term)
__device__ __forceinline__ float posswap(float x) {
  float e  = __expf(-x);
  float u  = 1.f + e;
  float r  = __builtin_amdgcn_rcpf(u);
  float lu = __logf(u);
  float omp = e * r;                     // 1-p
  return 0.25f * omp * omp * lu - 0.75f * (x + lu) * (r * r);
}

// smooth-L1 of one prior (SSD encode + compare), reference op order
__device__ __forceinline__ float smoothl1(float4 pl, float4 bx, float4 pc) {
  float cx = (bx.x + bx.z) * 0.5f;
  float cy = (bx.y + bx.w) * 0.5f;
  float cw = bx.z - bx.x;
  float ch = bx.w - bx.y;
  float gx = (cx - pc.x) / (pc.z / 10.f);    // keep the /10. division
  float gy = (cy - pc.y) / (pc.w / 10.f);
  float gw = logf(cw / pc.z) * 5.f;
  float gh = logf(ch / pc.w) * 5.f;
  float s = 0.f, d, a;
  d = pl.x - gx; a = fabsf(d); s += (a < 1.f) ? 0.5f * d * d : a - 0.5f;
  d = pl.y - gy; a = fabsf(d); s += (a < 1.f) ? 0.5f * d * d : a - 0.5f;
  d = pl.z - gw; a = fabsf(d); s += (a < 1.f) ? 0.5f * d * d : a - 0.5f;
  d = pl.w - gh; a = fabsf(d); s += (a < 1.f) ? 0.5f * d * d : a - 0.5f;
  return s;
}

// ---------------------------------------------------------------- K1: bulk focal + UNFORCED match + objbest
// Bulk-role blocks [0,NBLK): coalesced focal (R7 layout) with LDS-transpose
// per-prior rowsums consumed IN-BLOCK; unforced match (IoU argmax), label,
// ignore-subtract, positive pos-swap + smooth-L1 + npos -> per-block partials.
// objbest-role blocks [NBLK,NBLK+OBJB): per-object argmax over priors
// (packed (iou_bits<<32)|~prior, IEEE div for reference-bit IoU ordering).
__global__ __launch_bounds__(256, 4) void k_main(
    const float4* __restrict__ plocs, const float4* __restrict__ scores,
    const float* __restrict__ scoresF, const float4* __restrict__ boxes,
    const int* __restrict__ labels, const float4* __restrict__ priors,
    unsigned long long* __restrict__ objbest,
    float* __restrict__ partF, float* __restrict__ partS,
    int* __restrict__ partN) {
  const int bid = blockIdx.x;
  const int tid = threadIdx.x;
  if (bid < NBLK) {
    __shared__ float  sq[256 * RPAD];          // 21.5 KB
    __shared__ float4 sbox[NOBJ];
    __shared__ float  sarea[NOBJ];
    __shared__ int    slab[NOBJ];
    const int b    = bid / CHUNKS;
    const int c    = bid - b * CHUNKS;
    const int base = c * 256;
    const int nval = (P - base < 256) ? (P - base) : 256;
    if (tid < NOBJ) {
      float4 bx = boxes[b * NOBJ + tid];
      sbox[tid]  = bx;
      sarea[tid] = (bx.z - bx.x) * (bx.w - bx.y);  // reference op order
      slab[tid]  = labels[b * NOBJ + tid];
    }
    // ---- phase A: bulk focal, coalesced, per-float4 q -> LDS transpose
    const float4* srow = scores + ((size_t)b * P + base) * 20;
    float acc = 0.f;
    if (nval == 256) {
      #pragma unroll
      for (int bt = 0; bt < 2; ++bt) {
        float4 s[10];
        const int i0 = tid + bt * 2560;
        #pragma unroll
        for (int j = 0; j < 10; ++j) s[j] = srow[i0 + j * 256];  // coalesced
        #pragma unroll
        for (int j = 0; j < 10; ++j) {
          const int idx = i0 + j * 256;
          float q = negterm(s[j].x) + negterm(s[j].y)
                  + negterm(s[j].z) + negterm(s[j].w);
          acc += q;
          const int pl = idx / 20;
          sq[pl * RPAD + (idx - pl * 20)] = q;
        }
      }
    } else {
      for (int i = tid; i < 256 * RPAD; i += 256) sq[i] = 0.f;
      __syncthreads();
      const int lim = nval * 20;
      for (int idx = tid; idx < lim; idx += 256) {
        float4 s = srow[idx];
        float q = negterm(s.x) + negterm(s.y) + negterm(s.z) + negterm(s.w);
        acc += q;
        const int pl = idx / 20;
        sq[pl * RPAD + (idx - pl * 20)] = q;
      }
    }
    __syncthreads();
    // ---- phase B: per-prior rowsum (pad-21 -> conflict-free)
    float rsum = 0.f;
    if (tid < nval) {
      #pragma unroll
      for (int j = 0; j < 20; ++j) rsum += sq[tid * RPAD + j];
      rsum *= 0.75f;
    }
    // ---- phase C: unforced match
    const bool live = tid < nval;
    const int p = base + (live ? tid : 0);
    float4 pc = priors[p];
    float hx = pc.z * 0.5f, hy = pc.w * 0.5f;    // c/2. == c*0.5f exactly
    float px0 = pc.x - hx, py0 = pc.y - hy;
    float px1 = pc.x + hx, py1 = pc.y + hy;
    float parea = (px1 - px0) * (py1 - py0);
    float ov = -1.f; int obj = 0;
    #pragma unroll 8
    for (int o = 0; o < NOBJ; ++o) {
      float4 bx = sbox[o];
      float lx = fmaxf(bx.x, px0), ly = fmaxf(bx.y, py0);
      float rx = fminf(bx.z, px1), ry = fminf(bx.w, py1);
      float w = fmaxf(rx - lx, 0.f), h = fmaxf(ry - ly, 0.f);
      float inter = w * h;
      float iou = inter / (sarea[o] + parea - inter);  // IEEE div: ref bits
      if (iou > ov) { ov = iou; obj = o; }       // strict >: first max wins
    }
    // ---- phase D: unforced label + contributions
    float mySl1 = 0.f, corr = 0.f; int myPos = 0;
    if (live) {
      int lab = (ov < 0.4f) ? 0 : (ov < 0.5f) ? -1 : slab[obj];
      if (lab < 0) {
        corr -= rsum;                            // ignore: remove bulk row
      } else if (lab > 0) {
        myPos = 1;
        mySl1 = smoothl1(plocs[(size_t)b * P + p], sbox[obj], pc);
        corr += posswap(scoresF[((size_t)b * P + p) * NCLS + (lab - 1)]);
      }
    }
    float myF = 0.75f * acc + corr;
    for (int off = 32; off > 0; off >>= 1) {
      myF   += __shfl_down(myF,   off, 64);
      mySl1 += __shfl_down(mySl1, off, 64);
      myPos += __shfl_down(myPos, off, 64);
    }
    __shared__ float svF[4], svS[4];
    __shared__ int   svP[4];
    int lane = tid & 63, wid = tid >> 6;
    if (lane == 0) { svF[wid] = myF; svS[wid] = mySl1; svP[wid] = myPos; }
    __syncthreads();
    if (tid == 0) {
      partF[bid] = svF[0] + svF[1] + svF[2] + svF[3];
      partS[bid] = svS[0] + svS[1] + svS[2] + svS[3];
      partN[bid] = svP[0] + svP[1] + svP[2] + svP[3];
    }
  } else {
    // -------- objbest role (unchanged, proven)
    const int bid2 = bid - NBLK;
    const int b = bid2 >> 5;
    const int o = bid2 & (NOBJ - 1);
    float4 bx = boxes[b * NOBJ + o];
    float barea = (bx.z - bx.x) * (bx.w - bx.y);
    unsigned long long best = 0ull;
    for (int p = tid; p < P; p += 256) {
      float4 pc = priors[p];
      float hx = pc.z * 0.5f, hy = pc.w * 0.5f;
      float px0 = pc.x - hx, py0 = pc.y - hy;
      float px1 = pc.x + hx, py1 = pc.y + hy;
      float parea = (px1 - px0) * (py1 - py0);
      float lx = fmaxf(bx.x, px0), ly = fmaxf(bx.y, py0);
      float rx = fminf(bx.z, px1), ry = fminf(bx.w, py1);
      float w = fmaxf(rx - lx, 0.f), h = fmaxf(ry - ly, 0.f);
      float inter = w * h;
      float iou = inter / (barea + parea - inter);
      unsigned long long pk =
          ((unsigned long long)__float_as_uint(iou) << 32) |
          (unsigned long long)(unsigned)(~(unsigned)p);
      best = (pk > best) ? pk : best;
    }
    for (int off = 32; off > 0; off >>= 1) {
      unsigned long long other = __shfl_down(best, off, 64);
      best = (other > best) ? other : best;
    }
    __shared__ unsigned long long sb[4];
    int lane = tid & 63, wid = tid >> 6;
    if (lane == 0) sb[wid] = best;
    __syncthreads();
    if (tid == 0) {
      unsigned long long r = sb[0];
      r = (sb[1] > r) ? sb[1] : r;
      r = (sb[2] > r) ? sb[2] : r;
      r = (sb[3] > r) ? sb[3] : r;
      objbest[bid2] = r;
    }
  }
}

// ---------------------------------------------------------------- K2: forced-prior fix-ups + final reduce
// One block, 512 threads = one lane per (image b, object o). Forced-list via
// ballot prefix (= cumsum(valid)-1 quirk); duplicate forced priors: last
// valid j wins (reference scatter order). Winners recompute their prior's
// UNFORCED state bit-identically and apply undo/redo deltas. Then reduce all
// per-block partials + deltas and write the scalar loss.
__global__ __launch_bounds__(512) void k_fix(
    const float4* __restrict__ plocs, const float* __restrict__ scoresF,
    const float4* __restrict__ boxes, const int* __restrict__ labels,
    const float4* __restrict__ priors,
    const unsigned long long* __restrict__ objbest,
    const float* __restrict__ partF, const float* __restrict__ partS,
    const int* __restrict__ partN, float* __restrict__ out) {
  const int tid = threadIdx.x;          // tid = b*32 + o
  const int b = tid >> 5, o = tid & 31;
  __shared__ float4 sbox[OBJB];
  __shared__ float  sarea[OBJB];
  __shared__ int    slab[OBJB];
  __shared__ int    sfp[OBJB];
  float4 bx = boxes[tid];               // coalesced: all 512 boxes
  sbox[tid]  = bx;
  sarea[tid] = (bx.z - bx.x) * (bx.w - bx.y);
  slab[tid]  = labels[tid];
  unsigned long long pk = objbest[tid];
  float iou = __uint_as_float((unsigned)(pk >> 32));
  bool valid = iou > 0.f;
  int fp = valid ? (int)(~(unsigned)(pk & 0xFFFFFFFFull)) : -1;
  sfp[tid] = fp;
  // filtered index: valid-count among objects o'<o of the same image.
  // Wave w holds images 2w (lanes 0-31) and 2w+1 (lanes 32-63).
  unsigned long long bal = __ballot(valid);
  unsigned mask = (unsigned)(bal >> (tid & 32));
  int filt = __popc(mask & ((1u << o) - 1u));
  __syncthreads();
  bool winner = (fp >= 0);
  if (winner) {                          // last valid j with this prior wins
    for (int o2 = o + 1; o2 < NOBJ; ++o2)
      if (sfp[(b << 5) + o2] == fp) { winner = false; break; }
  }
  float dF = 0.f, dS = 0.f; int dN = 0;
  if (winner) {
    float4 pc = priors[fp];
    float hx = pc.z * 0.5f, hy = pc.w * 0.5f;
    float px0 = pc.x - hx, py0 = pc.y - hy;
    float px1 = pc.x + hx, py1 = pc.y + hy;
    float parea = (px1 - px0) * (py1 - py0);
    float ov0 = -1.f; int obj0 = 0;
    for (int oo = 0; oo < NOBJ; ++oo) {  // bit-identical to K1 phase C
      float4 bb = sbox[(b << 5) + oo];
      float lx = fmaxf(bb.x, px0), ly = fmaxf(bb.y, py0);
      float rx = fminf(bb.z, px1), ry = fminf(bb.w, py1);
      float w = fmaxf(rx - lx, 0.f), h = fmaxf(ry - ly, 0.f);
      float inter = w * h;
      float iou2 = inter / (sarea[(b << 5) + oo] + parea - inter);
      if (iou2 > ov0) { ov0 = iou2; obj0 = oo; }
    }
    const size_t rowbase = ((size_t)b * P + fp) * NCLS;
    float4 pl = plocs[(size_t)b * P + fp];
    int lab0 = (ov0 < 0.4f) ? 0 : (ov0 < 0.5f) ? -1 : slab[(b << 5) + obj0];
    if (lab0 < 0) {
      // K1 subtracted this row's bulk; re-add (recompute, same op order)
      const float4* row = (const float4*)(scoresF + rowbase);
      float rs = 0.f;
      for (int j = 0; j < 20; ++j) {
        float4 s = row[j];
        rs += negterm(s.x) + negterm(s.y) + negterm(s.z) + negterm(s.w);
      }
      dF += 0.75f * rs;
    } else if (lab0 > 0) {
      dN -= 1;
      dS -= smoothl1(pl, sbox[(b << 5) + obj0], pc);
      dF -= posswap(scoresF[rowbase + (lab0 - 1)]);
    }
    int labF = slab[(b << 5) + filt];    // quirky filtered-index lookup
    dN += 1;
    dS += smoothl1(pl, sbox[(b << 5) + filt], pc);
    dF += posswap(scoresF[rowbase + (labF - 1)]);
  }
  // ---- final reduce: partials + deltas
  float sF = dF, sS = dS; int sN = dN;
  for (int i = tid; i < NBLK; i += 512) {
    sF += partF[i]; sS += partS[i]; sN += partN[i];
  }
  for (int off = 32; off > 0; off >>= 1) {
    sF += __shfl_down(sF, off, 64);
    sS += __shfl_down(sS, off, 64);
    sN += __shfl_down(sN, off, 64);
  }
  __shared__ float vF[8], vS[8];
  __shared__ int   vN[8];
  int lane = tid & 63, wid = tid >> 6;
  if (lane == 0) { vF[wid] = sF; vS[wid] = sS; vN[wid] = sN; }
  __syncthreads();
  if (tid == 0) {
    float f = 0.f, s = 0.f; int n = 0;
    #pragma unroll
    for (int w2 = 0; w2 < 8; ++w2) { f += vF[w2]; s += vS[w2]; n += vN[w2]; }
    float np = (float)(n >= 1 ? n : 1);
    out[0] = f / np + s / (np * 4.f);
  }
}

// ---------------------------------------------------------------- launch
extern "C" void kernel_launch(void* const* d_in, const int* in_sizes, int n_in,
                              void* d_out, int out_size, void* d_ws, size_t ws_size,
                              hipStream_t stream) {
  const float* plocs   = (const float*)d_in[0];   // [B,P,4]
  const float* pscores = (const float*)d_in[1];   // [B,P,80]
  const float* boxes   = (const float*)d_in[2];   // [B,32,4]
  const int*   labels  = (const int*)d_in[3];     // [B,32]
  const float* priors  = (const float*)d_in[4];   // [P,4]
  float* out = (float*)d_out;

  char* w = (char*)d_ws;
  unsigned long long* objbest = (unsigned long long*)w;  // 512 u64  @0
  float* partF = (float*)(w + 4096);                     // NBLK floats
  float* partS = (float*)(w + 16384);                    // NBLK floats
  int*   partN = (int*)(w + 28672);                      // NBLK ints

  k_main<<<NBLK + OBJB, 256, 0, stream>>>(
      (const float4*)plocs, (const float4*)pscores, pscores,
      (const float4*)boxes, labels, (const float4*)priors,
      objbest, partF, partS, partN);
  k_fix<<<1, 512, 0, stream>>>(
      (const float4*)plocs, pscores, (const float4*)boxes, labels,
      (const float4*)priors, objbest, partF, partS, partN, out);
}